// Round 2
// baseline (434.607 us; speedup 1.0000x reference)
//
#include <hip/hip_runtime.h>

#define K_DIM 4096
#define N_DIM 8192   // rows of x
#define M_DIM 4096   // rows of weight

typedef int v4i __attribute__((ext_vector_type(4)));

// ---------------- fused amax over x and w ----------------
// blocks [0,2048) reduce x -> scal[0]; blocks [2048,3072) reduce w -> scal[1]
__global__ void amax2_kernel(const float4* __restrict__ x,
                             const float4* __restrict__ w,
                             unsigned* __restrict__ scal) {
  const int XB = 2048, WB = 1024;
  const float4* p;
  int n4, b, nb;
  unsigned* out;
  if (blockIdx.x < XB) {
    p = x; n4 = N_DIM * K_DIM / 4; out = scal + 0; b = blockIdx.x; nb = XB;
  } else {
    p = w; n4 = M_DIM * K_DIM / 4; out = scal + 1; b = blockIdx.x - XB; nb = WB;
  }
  int tid = b * blockDim.x + threadIdx.x;
  int stride = nb * blockDim.x;
  float m = 0.f;
  for (int i = tid; i < n4; i += stride) {
    float4 v = p[i];
    m = fmaxf(m, fmaxf(fmaxf(fabsf(v.x), fabsf(v.y)),
                       fmaxf(fabsf(v.z), fabsf(v.w))));
  }
#pragma unroll
  for (int off = 32; off > 0; off >>= 1)
    m = fmaxf(m, __shfl_down(m, off));
  __shared__ float sm[4];
  int lane = threadIdx.x & 63, wv = threadIdx.x >> 6;
  if (lane == 0) sm[wv] = m;
  __syncthreads();
  if (threadIdx.x == 0) {
    m = fmaxf(fmaxf(sm[0], sm[1]), fmaxf(sm[2], sm[3]));
    atomicMax(out, __float_as_uint(m));  // values >= 0: uint order == float order
  }
}

// ---------------- fused quantize fp32 -> int8, coalesced 4 elems/iter ------
__device__ __forceinline__ unsigned pack4(float4 v, float s) {
  int q0 = (int)fminf(fmaxf(rintf(v.x * s), -127.f), 127.f);
  int q1 = (int)fminf(fmaxf(rintf(v.y * s), -127.f), 127.f);
  int q2 = (int)fminf(fmaxf(rintf(v.z * s), -127.f), 127.f);
  int q3 = (int)fminf(fmaxf(rintf(v.w * s), -127.f), 127.f);
  return (unsigned)(q0 & 255) | ((unsigned)(q1 & 255) << 8) |
         ((unsigned)(q2 & 255) << 16) | ((unsigned)(q3 & 255) << 24);
}

__global__ void quant2_kernel(const float4* __restrict__ x,
                              const float4* __restrict__ w,
                              unsigned* __restrict__ qx, unsigned* __restrict__ qw,
                              const unsigned* __restrict__ scal) {
  const int XB = 2048, WB = 1024;
  const float4* in;
  unsigned* out;
  int n4, b, nb;
  float amax;
  if (blockIdx.x < XB) {
    in = x; out = qx; n4 = N_DIM * K_DIM / 4; b = blockIdx.x; nb = XB;
    amax = __uint_as_float(scal[0]);
  } else {
    in = w; out = qw; n4 = M_DIM * K_DIM / 4; b = blockIdx.x - XB; nb = WB;
    amax = __uint_as_float(scal[1]);
  }
  float s = 127.0f / amax;
  int tid = b * blockDim.x + threadIdx.x;
  int stride = nb * blockDim.x;
  for (int i = tid; i < n4; i += stride) out[i] = pack4(in[i], s);
}

// ---------------- int8 GEMM: out = qx (N,K) * qw^T (K,M), dequant + bias ----
__device__ __forceinline__ void gld_lds16(const void* g, void* l) {
  __builtin_amdgcn_global_load_lds(
      (const __attribute__((address_space(1))) void*)g,
      (__attribute__((address_space(3))) void*)l, 16, 0, 0);
}

// 256x256 tile, BK=64 bytes, 8 waves (2M x 4N), 4-slot LDS ring (128 KiB).
// 8-phase-style schedule: per K-tile, 2 phases {ds_read subtile || 2 stage
// loads -> barrier -> lgkmcnt(0) -> setprio(1) -> 16 MFMA -> setprio(0) ->
// barrier}. Tile T+3 is staged into the slot freed by tile T-1 (4-6 phases
// of load lead); one counted vmcnt(8) per tile, never 0 in steady state.
// LDS layout per slot/operand: 256 logical rows folded into [128 phys rows]
// [8 chunks x 16B]; chunk = ((half<<2)|fq) ^ (physrow&7) (proven 0-conflict).
__global__ __launch_bounds__(512, 2) void gemm_i8(
    const signed char* __restrict__ A,   // qx  [N_DIM][K_DIM]
    const signed char* __restrict__ B,   // qw  [M_DIM][K_DIM]
    const float* __restrict__ bias,      // [M_DIM]
    float* __restrict__ out,             // [N_DIM][M_DIM]
    const unsigned* __restrict__ scal)   // [0]=amax_x bits [1]=amax_w bits
{
  __shared__ signed char lds[4][2][128 * 128];  // [slot][A/B][phys] = 128 KiB

  const int tid = threadIdx.x;
  const int lane = tid & 63;
  const int w = tid >> 6;      // wave 0..7
  const int wm = w >> 2;       // 0..1  (row half of 256)
  const int wn = w & 3;        // 0..3  (col quarter of 256)

  // XCD-aware bijective swizzle: 512 wgs, 8 XCDs, each gets an 8x8 region
  const int bid = blockIdx.x;
  const int xcd = bid & 7, idx = bid >> 3;     // 512 % 8 == 0: bijective
  const int bx = (xcd & 3) * 8 + (idx & 7);    // 0..31 (N tiles)
  const int by = (xcd >> 2) * 8 + (idx >> 3);  // 0..15 (M tiles)
  const long r0 = (long)bx * 256;
  const long c0 = (long)by * 256;

  // staging: instr p covers phys rows 64p..64p+63; thread t -> phys row
  // 64p+(t>>3), phys chunk t&7 (linear dest). Source applies inverse swizzle:
  // u = (t&7)^((t>>3)&7); logical row = (u>>2)*128 + 64p + (t>>3); kcol = u&3.
  const int u = (tid & 7) ^ ((tid >> 3) & 7);
  const long sR = (long)(u >> 2) * 128 + (tid >> 3);
  const int scol = (u & 3) * 16;
  const signed char* gA = A + (r0 + sR) * K_DIM + scol;
  const signed char* gB = B + (c0 + sR) * K_DIM + scol;
  const int ldst = tid * 16;

  v4i acc[8][4];
#pragma unroll
  for (int i = 0; i < 8; ++i)
#pragma unroll
    for (int j = 0; j < 4; ++j) acc[i][j] = (v4i){0, 0, 0, 0};

  const int fr = lane & 15;   // fragment row (m or n)
  const int fq = lane >> 4;   // 16B k-chunk
  const int sw = fr & 7;      // swizzle key

  // fragment read base offsets (phys addressing within a slot's operand block)
  const int aoff = fr * 128 + (((wm << 2) | fq) ^ sw) * 16;
  const int boff = ((wn & 1) * 64 + fr) * 128 + ((((wn >> 1) << 2) | fq) ^ sw) * 16;

  auto STAGE = [&](int T, int p) {
    signed char* la = &lds[T & 3][0][0];
    signed char* lb = &lds[T & 3][1][0];
    gld_lds16(gA + (long)p * 64 * K_DIM + T * 64, la + p * 8192 + ldst);
    gld_lds16(gB + (long)p * 64 * K_DIM + T * 64, lb + p * 8192 + ldst);
  };

  auto TILE = [&](int T, bool stg, int guard) {
    const signed char* la = &lds[T & 3][0][0];
    const signed char* lb = &lds[T & 3][1][0];
    v4i bv[4], a0[4], a1[4];
    // ---- phase 0 (mh=0) ----
#pragma unroll
    for (int nf = 0; nf < 4; ++nf)
      bv[nf] = *(const v4i*)(lb + boff + nf * 2048);
#pragma unroll
    for (int mi = 0; mi < 4; ++mi)
      a0[mi] = *(const v4i*)(la + aoff + mi * 2048);
    if (stg) STAGE(T + 3, 0);
    __builtin_amdgcn_s_barrier();
    asm volatile("s_waitcnt lgkmcnt(0)" ::: "memory");
    __builtin_amdgcn_s_setprio(1);
#pragma unroll
    for (int mi = 0; mi < 4; ++mi)
#pragma unroll
      for (int nf = 0; nf < 4; ++nf)
        acc[mi][nf] = __builtin_amdgcn_mfma_i32_16x16x64_i8(a0[mi], bv[nf],
                                                            acc[mi][nf], 0, 0, 0);
    __builtin_amdgcn_s_setprio(0);
    __builtin_amdgcn_s_barrier();
    // ---- phase 1 (mh=1) ----
#pragma unroll
    for (int mi = 0; mi < 4; ++mi)
      a1[mi] = *(const v4i*)(la + aoff + 8192 + mi * 2048);
    if (stg) STAGE(T + 3, 1);
    // guard tile T+1: keep tiles T+2,T+3 (8 loads) in flight
    if (guard == 8) asm volatile("s_waitcnt vmcnt(8)" ::: "memory");
    else if (guard == 4) asm volatile("s_waitcnt vmcnt(4)" ::: "memory");
    else if (guard == 0) asm volatile("s_waitcnt vmcnt(0)" ::: "memory");
    __builtin_amdgcn_s_barrier();
    asm volatile("s_waitcnt lgkmcnt(0)" ::: "memory");
    __builtin_amdgcn_s_setprio(1);
#pragma unroll
    for (int mi = 0; mi < 4; ++mi)
#pragma unroll
      for (int nf = 0; nf < 4; ++nf)
        acc[4 + mi][nf] = __builtin_amdgcn_mfma_i32_16x16x64_i8(
            a1[mi], bv[nf], acc[4 + mi][nf], 0, 0, 0);
    __builtin_amdgcn_s_setprio(0);
    __builtin_amdgcn_s_barrier();
  };

  const int NT = K_DIM / 64;  // 64 K-tiles
  // prologue: stage tiles 0,1,2 (12 loads); drain tile 0 (keep 8 in flight)
#pragma unroll
  for (int T = 0; T < 3; ++T) { STAGE(T, 0); STAGE(T, 1); }
  asm volatile("s_waitcnt vmcnt(8)" ::: "memory");
  __builtin_amdgcn_s_barrier();

#pragma unroll 1
  for (int T = 0; T + 4 <= NT; ++T) TILE(T, true, 8);   // T = 0..NT-4
  TILE(NT - 3, false, 4);
  TILE(NT - 2, false, 0);
  TILE(NT - 1, false, -1);

  const float dq =
      (__uint_as_float(scal[0]) * __uint_as_float(scal[1])) / 16129.0f;
  float bs[4];
#pragma unroll
  for (int nf = 0; nf < 4; ++nf) bs[nf] = bias[c0 + wn * 64 + nf * 16 + fr];

#pragma unroll
  for (int mf = 0; mf < 8; ++mf) {
    const long rbase = r0 + wm * 128 + mf * 16 + fq * 4;  // C/D row=(lane>>4)*4+reg
#pragma unroll
    for (int nf = 0; nf < 4; ++nf) {
      const long c = c0 + wn * 64 + nf * 16 + fr;         // C/D col=lane&15
#pragma unroll
      for (int t = 0; t < 4; ++t) {
        out[(rbase + t) * (long)M_DIM + c] = (float)acc[mf][nf][t] * dq + bs[nf];
      }
    }
  }
}

extern "C" void kernel_launch(void* const* d_in, const int* in_sizes, int n_in,
                              void* d_out, int out_size, void* d_ws, size_t ws_size,
                              hipStream_t stream) {
  const float* x = (const float*)d_in[0];      // [8192,4096]
  const float* wt = (const float*)d_in[1];     // [4096,4096]
  const float* bias = (const float*)d_in[2];   // [4096]
  float* out = (float*)d_out;

  unsigned* scal = (unsigned*)d_ws;                       // 2 scalars
  signed char* qx = (signed char*)d_ws + 256;             // 32 MiB
  signed char* qw = qx + (long)N_DIM * K_DIM;             // 16 MiB

  hipMemsetAsync(d_ws, 0, 16, stream);  // zero amax slots (ws poisoned 0xAA)

  amax2_kernel<<<3072, 256, 0, stream>>>((const float4*)x, (const float4*)wt,
                                         scal);
  quant2_kernel<<<3072, 256, 0, stream>>>((const float4*)x, (const float4*)wt,
                                          (unsigned*)qx, (unsigned*)qw, scal);

  gemm_i8<<<512, 512, 0, stream>>>(qx, qw, bias, out, scal);
}